// Round 2
// baseline (132.023 us; speedup 1.0000x reference)
//
#include <hip/hip_runtime.h>
#include <stdint.h>

#define NGRAPH 512
#define NN 64
#define INCH 256
#define DD 64
#define TOPK 20
#define XS 68            // f32 LDS row stride: 16B-aligned, odd*4 banks per row
#define EPR 655360       // elements per output section (B*n*k)

typedef __attribute__((ext_vector_type(8))) short bf16x8;
typedef __attribute__((ext_vector_type(4))) float f32x4;

static __device__ __forceinline__ uint32_t f2bfbits(float f) {
  uint32_t u = __float_as_uint(f);
  return (u + 0x7FFFu + ((u >> 16) & 1u)) >> 16;   // RNE
}
static __device__ __forceinline__ uint32_t pk2(float a, float b) {
  return f2bfbits(a) | (f2bfbits(b) << 16);
}

__global__ __launch_bounds__(256) void gat_fused(
    const float* __restrict__ x,    // [32768,256] f32
    const float* __restrict__ Wl,   // [64,256]
    const float* __restrict__ blv,  // [64]
    const float* __restrict__ Wr,   // [64,256]
    const float* __restrict__ brv,  // [64]
    const float* __restrict__ att,  // [64]
    float* __restrict__ out)        // f32: [idx_i EPR | idx_j EPR | att EPR]
{
  // 64KB region: W-staging (bf16, swizzled) during GEMM, then reused for xlT/xrT/alfT
  __shared__ __align__(16) uint8_t smem[65536];
  __shared__ float attL[DD];
  __shared__ float Sl[NN], Sr[NN];

  uint32_t* Bsh = (uint32_t*)smem;                 // 128 rows x 256 bf16 (pairs)
  float* xlT  = (float*)smem;                      // [DD][XS]  (17408 B)
  float* xrT  = (float*)(smem + 17408);            // [DD][XS]
  float* alfT = (float*)(smem + 34816);            // [NN][XS]  alfT[j][i]

  const int b    = blockIdx.x;
  const int t    = threadIdx.x;
  const int w    = t >> 6;
  const int lane = t & 63;
  const int quad = lane >> 4;
  const int lo   = lane & 15;
  const int nodeBase = b * NN;

  // ---------- phase 0: stage W (f32 -> bf16 RNE) into LDS, XOR-swizzled 16B blocks ----
  {
    const int row  = t >> 1;                       // 0..127 (0..63 Wl, 64..127 Wr)
    const int half = t & 1;
    const float* src = (row < 64) ? (Wl + row * INCH) : (Wr + (row - 64) * INCH);
    uint4* BshV = (uint4*)Bsh;
    #pragma unroll
    for (int q = 0; q < 16; ++q) {
      const int kb = half * 16 + q;                // 16B block index 0..31
      float4 a = *(const float4*)(src + kb * 8);
      float4 c = *(const float4*)(src + kb * 8 + 4);
      uint4 v = { pk2(a.x, a.y), pk2(a.z, a.w), pk2(c.x, c.y), pk2(c.z, c.w) };
      BshV[row * 32 + (kb ^ (row & 7))] = v;
    }
    if (t < DD) attL[t] = att[t];
  }
  __syncthreads();

  // ---------- phase 1: MFMA GEMM  [64x256] @ [256x128] -> xl,xr ------------------
  // wave w owns rows r0..r0+15; ct 0..3 -> Wl cols, 4..7 -> Wr cols
  f32x4 acc[8];
  #pragma unroll
  for (int ct = 0; ct < 8; ++ct) acc[ct] = (f32x4){0.f, 0.f, 0.f, 0.f};

  const int r0 = w * 16;
  const uint4* BshV = (const uint4*)Bsh;
  #pragma unroll
  for (int ks = 0; ks < 8; ++ks) {
    // A frag: x[node][ks*32 + quad*8 .. +8], fp32 -> bf16
    const float* ap = x + (size_t)(nodeBase + r0 + lo) * INCH + ks * 32 + quad * 8;
    float4 a0 = *(const float4*)ap;
    float4 a1 = *(const float4*)(ap + 4);
    uint4 au = { pk2(a0.x, a0.y), pk2(a0.z, a0.w), pk2(a1.x, a1.y), pk2(a1.z, a1.w) };
    bf16x8 afrag = __builtin_bit_cast(bf16x8, au);
    #pragma unroll
    for (int ct = 0; ct < 8; ++ct) {
      const int n = (ct & 3) * 16 + lo + ((ct >= 4) ? 64 : 0);   // W row = output col d
      const int blk = (ks * 4 + quad) ^ (n & 7);
      uint4 bu = BshV[n * 32 + blk];
      bf16x8 bfrag = __builtin_bit_cast(bf16x8, bu);
      acc[ct] = __builtin_amdgcn_mfma_f32_16x16x32_bf16(afrag, bfrag, acc[ct], 0, 0, 0);
    }
  }
  __syncthreads();   // staging region dead; safe to overwrite with xlT/xrT

  // ---------- phase 1.5: C/D frags (col=lo, row=quad*4+r) -> LDS transposed + bias --
  #pragma unroll
  for (int ct = 0; ct < 8; ++ct) {
    const int c = (ct & 3) * 16 + lo;              // d in 0..63
    const float bias = (ct < 4) ? blv[c] : brv[c];
    float* dstT = (ct < 4) ? xlT : xrT;
    #pragma unroll
    for (int r = 0; r < 4; ++r) {
      const int node = r0 + quad * 4 + r;
      dstT[c * XS + node] = acc[ct][r] + bias;
    }
  }
  __syncthreads();

  // ---------- phase 2: alpha_ij = 0.6*(Sl_i+Sr_j) + 0.4*sum_d a_d*|xl_id+xr_jd| ----
  if (t < 64) {            // Sl_i = sum_d a_d * xl[i][d]
    float s = 0.f;
    for (int d = 0; d < DD; ++d) s = fmaf(attL[d], xlT[d * XS + t], s);
    Sl[t] = s;
  } else if (t < 128) {
    const int i = t - 64;
    float s = 0.f;
    for (int d = 0; d < DD; ++d) s = fmaf(attL[d], xrT[d * XS + i], s);
    Sr[i] = s;
  }

  const int i0 = (t >> 4) * 4;
  const int j0 = (t & 15) * 4;
  float pacc[4][4];
  #pragma unroll
  for (int a = 0; a < 4; ++a)
    #pragma unroll
    for (int c = 0; c < 4; ++c) pacc[a][c] = 0.f;

  for (int d = 0; d < DD; ++d) {
    f32x4 xlv = *(const f32x4*)&xlT[d * XS + i0];
    f32x4 xrv = *(const f32x4*)&xrT[d * XS + j0];
    const float ad = attL[d];
    #pragma unroll
    for (int a = 0; a < 4; ++a) {
      #pragma unroll
      for (int c = 0; c < 4; ++c) {
        float s = xlv[a] + xrv[c];
        pacc[a][c] = fmaf(ad, fabsf(s), pacc[a][c]);   // abs folds into VOP3 modifier
      }
    }
  }
  __syncthreads();   // Sl/Sr visible; xlT/xrT reads done

  #pragma unroll
  for (int c = 0; c < 4; ++c) {
    f32x4 v;
    #pragma unroll
    for (int a = 0; a < 4; ++a)
      v[a] = 0.6f * (Sl[i0 + a] + Sr[j0 + c]) + 0.4f * pacc[a][c];
    *(f32x4*)&alfT[(j0 + c) * XS + i0] = v;            // alfT[j][i]
  }
  __syncthreads();

  // ---------- phase 3: softmax + top-20 per row (thread i = row) -------------------
  if (t < NN) {
    const int i = t;
    float m = -3.4e38f;
    for (int j = 0; j < NN; ++j) m = fmaxf(m, alfT[j * XS + i]);
    float ssum = 0.f;
    for (int j = 0; j < NN; ++j) ssum += __expf(alfT[j * XS + i] - m);
    const float inv = 1.0f / ssum;

    // key: fp32 bits of a (a>=0, monotone) with low 6 mantissa bits = 63-j
    // -> desc by value, asc by index on ties (matches jax top_k)
    uint32_t tk[TOPK];
    #pragma unroll
    for (int k = 0; k < TOPK; ++k) tk[k] = 0u;

    for (int j = 0; j < NN; ++j) {
      const float av = __expf(alfT[j * XS + i] - m) * inv;
      uint32_t key = (__float_as_uint(av) & 0xFFFFFFC0u) | (uint32_t)(63 - j);
      key = (j == i) ? 0u : key;                 // zeroed diagonal never in top-20
      #pragma unroll
      for (int k = TOPK - 1; k >= 1; --k)
        tk[k] = (key > tk[k]) ? ((key < tk[k - 1]) ? key : tk[k - 1]) : tk[k];
      tk[0] = (key > tk[0]) ? key : tk[0];
    }

    const int g = nodeBase + i;
    float vj[TOPK], va[TOPK];
    #pragma unroll
    for (int k = 0; k < TOPK; ++k) {
      const int jj = 63 - (int)(tk[k] & 63u);
      vj[k] = (float)(nodeBase + jj);
      va[k] = __uint_as_float(tk[k] & 0xFFFFFFC0u);
    }

    const float vi = (float)g;
    float4* o0 = (float4*)(out + (size_t)g * 20);
    float4* o1 = (float4*)(out + EPR + (size_t)g * 20);
    float4* o2 = (float4*)(out + 2 * (size_t)EPR + (size_t)g * 20);
    const float4 vi4 = { vi, vi, vi, vi };
    #pragma unroll
    for (int kk = 0; kk < 5; ++kk) {
      o0[kk] = vi4;
      o1[kk] = (float4){ vj[4 * kk], vj[4 * kk + 1], vj[4 * kk + 2], vj[4 * kk + 3] };
      o2[kk] = (float4){ va[4 * kk], va[4 * kk + 1], va[4 * kk + 2], va[4 * kk + 3] };
    }
  }
}

extern "C" void kernel_launch(void* const* d_in, const int* in_sizes, int n_in,
                              void* d_out, int out_size, void* d_ws, size_t ws_size,
                              hipStream_t stream) {
  const float* x   = (const float*)d_in[0];
  // d_in[1] = edge_index (int32), d_in[2] = batch (int32): implicit structure, unused
  const float* Wl  = (const float*)d_in[3];
  const float* bl  = (const float*)d_in[4];
  const float* Wr  = (const float*)d_in[5];
  const float* br  = (const float*)d_in[6];
  const float* att = (const float*)d_in[7];
  gat_fused<<<dim3(NGRAPH), dim3(256), 0, stream>>>(x, Wl, bl, Wr, br, att, (float*)d_out);
}